// Round 18
// baseline (40.716 us; speedup 1.0000x reference)
//
#include <hip/hip_runtime.h>
#include <math.h>

namespace {
constexpr int NN = 256;   // graphs
constexpr int NV = 2048;  // vertices per graph
constexpr int NE = 64;    // embedding dim
constexpr int NH = 4;     // heads
}

typedef float vf4 __attribute__((ext_vector_type(4)));
typedef float f2  __attribute__((ext_vector_type(2)));

__device__ __forceinline__ f2 fma2(f2 a, f2 b, f2 c) {
    return __builtin_elementwise_fma(a, b, c);   // v_pk_fma_f32
}
// raw v_exp_f32: computes 2^x (no hidden mul, unlike __expf)
__device__ __forceinline__ float exp2r(float x) {
#if __has_builtin(__builtin_amdgcn_exp2f)
    return __builtin_amdgcn_exp2f(x);
#else
    return exp2f(x);
#endif
}

// DPP helpers (VALU pipe, no DS).  ctrl: 0xB1 quad_perm xor1, 0x4E xor2,
// 0x124 row_ror:4, 0x128 row_ror:8, j*0x55 quad_perm broadcast-lane-j.
template<int CTRL>
__device__ __forceinline__ float dpp_add(float x) {
    const int xi = __float_as_int(x);
    const int yi = __builtin_amdgcn_update_dpp(0, xi, CTRL, 0xF, 0xF, true);
    return x + __int_as_float(yi);
}
template<int CTRL>
__device__ __forceinline__ float dpp_mov(float x) {
    const int xi = __float_as_int(x);
    const int yi = __builtin_amdgcn_update_dpp(0, xi, CTRL, 0xF, 0xF, true);
    return __int_as_float(yi);
}

// ---------------- K0: qh = Wc @ query + bc  (256 outputs, once) -------------
__global__ void qh_kernel(const float* __restrict__ Wc,
                          const float* __restrict__ query,
                          const float* __restrict__ bc,
                          float* __restrict__ qh) {
    const int i = threadIdx.x;  // 0..255
    float acc = bc[i];
    #pragma unroll
    for (int k = 0; k < NE; k += 4) {
        const float4 w = *reinterpret_cast<const float4*>(Wc + i * NE + k);
        const float4 q = *reinterpret_cast<const float4*>(query + k);
        acc += w.x * q.x + w.y * q.y + w.z * q.z + w.w * q.w;
    }
    qh[i] = acc;
}

// ---------------- K1: single-pass logits + weighted partials ----------------
// R17 = R16 (best, 39.6us) with two residual trims:
// (a) rtL := rtemp*log2e pre-folded into wl/A at setup (they feed ONLY the
//     logit path) -> per-row weight becomes w = m * 2^(ssel + C2L): -3 VALU
//     per iter and the mask load leaves the exp dependency chain (R11's fold,
//     now isolated from the (256,5) confound that sank it).
// (b) #pragma unroll 8 (VGPR 60 of 128 cap -> headroom to hoist 8KB of loads
//     per backedge).
// 16-lane group owns one row: lane quad e = 4*(lane&15)+j, row group=lane>>4.
// tanh(x+qh) Taylor-expanded in qh (|qh|<=~0.006).  Z-counting: each lane's
// scalar zacc covers class lane&3; quads within a row are redundant copies,
// deduplicated in the epilogue by taking quad-0 lanes after xor16/32.
template<int CHUNKS>
__global__ __launch_bounds__(256, 4) void pool1_kernel(
    const float* __restrict__ vertices,
    const float* __restrict__ mask,
    const float* __restrict__ qh,
    const float* __restrict__ wl,
    const float* __restrict__ blp,
    const float* __restrict__ tempp,
    float* __restrict__ partN,    // [NN][CHUNKS][NH][NE]
    float* __restrict__ partZ)    // [NN][CHUNKS][NH]
{
    constexpr int ROWS_B = NV / CHUNKS;   // rows per block   (256 @ CHUNKS=8)
    constexpr int ROWS_W = ROWS_B / 4;    // rows per wave    (64)
    constexpr int ITERS  = ROWS_W / 4;    // 4 rows per iter  (16)
    constexpr float L2E  = 1.4426950408889634f;   // log2(e)

    __shared__ float sp[4][NH][NE];   // 4 KB
    __shared__ float sz[4][NH];

    const int tid   = threadIdx.x;
    const int lane  = tid & 63;
    const int wid   = tid >> 6;
    const int n     = blockIdx.x / CHUNKS;
    const int chunk = blockIdx.x % CHUNKS;
    const int eq    = (lane & 15) * 4;    // e-quad base for this lane
    const int rg    = lane >> 4;          // row group 0..3 (16-lane DPP rows)
    const bool c0   = (lane & 1) != 0;    // head-class select bits (hoisted)
    const bool c1   = (lane & 2) != 0;

    const float bl    = blp[0];
    const float rtemp = 1.0f / tempp[0];
    const float rtL   = rtemp * L2E;      // logit scale in log2 domain
    const float C2L   = bl * rtL;         // additive const in log2 domain

    // Per-lane constants straight from global (qh is 1 KB, L2-hot).
    // wl/A feed ONLY the logit path -> pre-scale by rtL here (trim a).
    const vf4 wlf = *reinterpret_cast<const vf4*>(wl + eq);
    f2 wl01 = __builtin_shufflevector(wlf, wlf, 0, 1);
    f2 wl23 = __builtin_shufflevector(wlf, wlf, 2, 3);
    f2 A01[NH], A23[NH];   // rtL * wl_j * qh[h][eq+j]
    #pragma unroll
    for (int h = 0; h < NH; ++h) {
        const vf4 q = *reinterpret_cast<const vf4*>(qh + h * NE + eq);
        A01[h] = (wl01 * rtL) * __builtin_shufflevector(q, q, 0, 1);
        A23[h] = (wl23 * rtL) * __builtin_shufflevector(q, q, 2, 3);
    }
    wl01 = wl01 * rtL;
    wl23 = wl23 * rtL;

    f2 nacc01[NH] = {}, nacc23[NH] = {};
    float zacc = 0.f;                          // class h = lane&3

    const float* vb = vertices + (size_t)n * NV * NE;
    const float* mb = mask + (size_t)n * NV;
    const int rbase = chunk * ROWS_B + wid * ROWS_W;

    #pragma unroll 8
    for (int it = 0; it < ITERS; ++it) {
        const int row = rbase + it * 4 + rg;
        const vf4   x = *reinterpret_cast<const vf4*>(vb + (size_t)row * NE + eq);
        const float m = mb[row];
        const f2 x01 = __builtin_shufflevector(x, x, 0, 1);
        const f2 x23 = __builtin_shufflevector(x, x, 2, 3);

        // t = tanh(x) = 1 - 2/(2^{2L2E*x}+1); u = 1 - t^2; s0 = sum wl*t
        const f2 z01 = x01 * (2.0f * L2E);           // pk_mul (folds exp's mul)
        const f2 z23 = x23 * (2.0f * L2E);
        f2 e01, e23;
        e01.x = exp2r(z01.x); e01.y = exp2r(z01.y);  // raw v_exp_f32
        e23.x = exp2r(z23.x); e23.y = exp2r(z23.y);
        const f2 d01 = e01 + 1.0f;
        const f2 d23 = e23 + 1.0f;
        f2 r01, r23;
        r01.x = __builtin_amdgcn_rcpf(d01.x); r01.y = __builtin_amdgcn_rcpf(d01.y);
        r23.x = __builtin_amdgcn_rcpf(d23.x); r23.y = __builtin_amdgcn_rcpf(d23.y);
        f2 m2; m2.x = -2.0f; m2.y = -2.0f;
        f2 one; one.x = 1.0f; one.y = 1.0f;
        const f2 t01 = fma2(m2, r01, one);
        const f2 t23 = fma2(m2, r23, one);
        const f2 u01 = fma2(-t01, t01, one);
        const f2 u23 = fma2(-t23, t23, one);
        f2 s0v = fma2(wl23, t23, wl01 * t01);        // already rtL-scaled

        // per-head partial -> 2-step quad sums (all 4 lanes of quad hold it)
        float q4[NH];
        #pragma unroll
        for (int h = 0; h < NH; ++h) {
            const f2 shv = fma2(A01[h], u01, fma2(A23[h], u23, s0v));
            float v = shv.x + shv.y;
            v = dpp_add<0xB1>(v);    // + lane^1
            v = dpp_add<0x4E>(v);    // + lane^2  -> quad sum
            q4[h] = v;
        }
        // lane class j = lane&3 picks head j; ror4+ror8 completes the row sum
        float ssel = c1 ? (c0 ? q4[3] : q4[2]) : (c0 ? q4[1] : q4[0]);
        ssel = dpp_add<0x124>(ssel);   // + row_ror:4
        ssel = dpp_add<0x128>(ssel);   // + row_ror:8 -> s[class] for this row
        // w for this lane's class: m * 2^(ssel + C2L); masked rows -> 0 exactly
        const float wsel = m * exp2r(ssel + C2L);
        zacc += wsel;
        // regather all 4 heads' w from within the quad
        const float w0 = dpp_mov<0x00>(wsel);
        const float w1 = dpp_mov<0x55>(wsel);
        const float w2 = dpp_mov<0xAA>(wsel);
        const float w3 = dpp_mov<0xFF>(wsel);
        f2 wv;
        wv.x = w0; wv.y = w0; nacc01[0] = fma2(wv, x01, nacc01[0]); nacc23[0] = fma2(wv, x23, nacc23[0]);
        wv.x = w1; wv.y = w1; nacc01[1] = fma2(wv, x01, nacc01[1]); nacc23[1] = fma2(wv, x23, nacc23[1]);
        wv.x = w2; wv.y = w2; nacc01[2] = fma2(wv, x01, nacc01[2]); nacc23[2] = fma2(wv, x23, nacc23[2]);
        wv.x = w3; wv.y = w3; nacc01[3] = fma2(wv, x01, nacc01[3]); nacc23[3] = fma2(wv, x23, nacc23[3]);
    }

    // unpack accumulators, reduce across the 4 row-groups
    float nacc[NH][4];
    #pragma unroll
    for (int h = 0; h < NH; ++h) {
        nacc[h][0] = nacc01[h].x; nacc[h][1] = nacc01[h].y;
        nacc[h][2] = nacc23[h].x; nacc[h][3] = nacc23[h].y;
    }
    #pragma unroll
    for (int off = 16; off <= 32; off <<= 1) {
        #pragma unroll
        for (int h = 0; h < NH; ++h) {
            #pragma unroll
            for (int j = 0; j < 4; ++j)
                nacc[h][j] += __shfl_xor(nacc[h][j], off, 64);
        }
        zacc += __shfl_xor(zacc, off, 64);
    }
    // zacc now: lane L holds sum over row-groups for class L&3, quad (L>>2)&3.
    // Quads are redundant copies of the same rows -> take quad 0 only.

    // cross-wave combine in LDS, then one partial per block to ws
    if (rg == 0) {  // lanes 0..15 hold the reduced values; eq = lane*4
        #pragma unroll
        for (int h = 0; h < NH; ++h) {
            sp[wid][h][eq + 0] = nacc[h][0];
            sp[wid][h][eq + 1] = nacc[h][1];
            sp[wid][h][eq + 2] = nacc[h][2];
            sp[wid][h][eq + 3] = nacc[h][3];
        }
        if (lane < NH) sz[wid][lane] = zacc;   // lane h = class h, quad 0
    }
    __syncthreads();
    {
        const int h = tid >> 6, e = tid & 63;
        const float v = sp[0][h][e] + sp[1][h][e] + sp[2][h][e] + sp[3][h][e];
        partN[(((size_t)n * CHUNKS + chunk) * NH + h) * NE + e] = v;
    }
    if (tid < NH) {
        const float z = sz[0][tid] + sz[1][tid] + sz[2][tid] + sz[3][tid];
        partZ[((size_t)n * CHUNKS + chunk) * NH + tid] = z;
    }
}

// ---------------- K2: reduce chunks, normalize, leaky, Wr matvec ------------
__global__ __launch_bounds__(256) void pool2_kernel(
    int chunks,
    const float* __restrict__ partN,
    const float* __restrict__ partZ,
    const float* __restrict__ Wr,
    const float* __restrict__ br,
    float* __restrict__ out)
{
    __shared__ float heads[NH * NE];
    const int n = blockIdx.x, tid = threadIdx.x;
    const int h = tid >> 6, e = tid & 63;

    float num = 0.f, Z = 0.f;
    for (int c = 0; c < chunks; ++c) {
        num += partN[(((size_t)n * chunks + c) * NH + h) * NE + e];
        Z   += partZ[((size_t)n * chunks + c) * NH + h];
    }
    const float val = num / Z;
    heads[tid] = (val > 0.f) ? val : 0.01f * val;
    __syncthreads();

    // out[n,e] = br[e] + sum_k heads[k] * Wr[e*256+k]; quad-split over k
    {
        const int eo = tid >> 2;          // 0..63 output element
        const int ko = (tid & 3) * 64;    // k sub-range
        float acc = 0.f;
        #pragma unroll
        for (int k = 0; k < 64; k += 4) {
            const float4 w = *reinterpret_cast<const float4*>(Wr + eo * (NH * NE) + ko + k);
            acc += heads[ko + k + 0] * w.x + heads[ko + k + 1] * w.y +
                   heads[ko + k + 2] * w.z + heads[ko + k + 3] * w.w;
        }
        acc += __shfl_xor(acc, 1, 64);
        acc += __shfl_xor(acc, 2, 64);
        if ((tid & 3) == 0) out[(size_t)n * NE + eo] = acc + br[eo];
    }
}

extern "C" void kernel_launch(void* const* d_in, const int* in_sizes, int n_in,
                              void* d_out, int out_size, void* d_ws, size_t ws_size,
                              hipStream_t stream) {
    const float* vertices = (const float*)d_in[0];
    const float* mask     = (const float*)d_in[1];
    const float* query    = (const float*)d_in[2];
    const float* Wc       = (const float*)d_in[3];
    const float* bc       = (const float*)d_in[4];
    const float* wl       = (const float*)d_in[5];
    const float* bl       = (const float*)d_in[6];
    const float* Wr       = (const float*)d_in[7];
    const float* br       = (const float*)d_in[8];
    const float* temp     = (const float*)d_in[9];
    float* out = (float*)d_out;

    // ws layout (floats): qh[256] | partZ[NN*chunks*NH] | partN[NN*chunks*NH*NE]
    auto need = [](int chunks) -> size_t {
        return (size_t)(256 + NN * chunks * NH + (size_t)NN * chunks * NH * NE) * 4;
    };
    int chunks = 8;
    while (chunks > 1 && need(chunks) > ws_size) chunks >>= 1;

    float* qh    = (float*)d_ws;
    float* partZ = qh + 256;
    float* partN = partZ + (size_t)NN * chunks * NH;

    qh_kernel<<<1, 256, 0, stream>>>(Wc, query, bc, qh);
    switch (chunks) {
        case 8:  pool1_kernel<8><<<NN * 8, 256, 0, stream>>>(vertices, mask, qh, wl, bl, temp, partN, partZ); break;
        case 4:  pool1_kernel<4><<<NN * 4, 256, 0, stream>>>(vertices, mask, qh, wl, bl, temp, partN, partZ); break;
        case 2:  pool1_kernel<2><<<NN * 2, 256, 0, stream>>>(vertices, mask, qh, wl, bl, temp, partN, partZ); break;
        default: pool1_kernel<1><<<NN * 1, 256, 0, stream>>>(vertices, mask, qh, wl, bl, temp, partN, partZ); break;
    }
    pool2_kernel<<<NN, 256, 0, stream>>>(chunks, partN, partZ, Wr, br, out);
}

// Round 19
// 39.071 us; speedup vs baseline: 1.0421x; 1.0421x over previous
//
#include <hip/hip_runtime.h>
#include <math.h>

namespace {
constexpr int NN = 256;   // graphs
constexpr int NV = 2048;  // vertices per graph
constexpr int NE = 64;    // embedding dim
constexpr int NH = 4;     // heads
}

typedef float vf4 __attribute__((ext_vector_type(4)));
typedef float f2  __attribute__((ext_vector_type(2)));

__device__ __forceinline__ f2 fma2(f2 a, f2 b, f2 c) {
    return __builtin_elementwise_fma(a, b, c);   // v_pk_fma_f32
}
// raw v_exp_f32: computes 2^x (no hidden mul, unlike __expf)
__device__ __forceinline__ float exp2r(float x) {
#if __has_builtin(__builtin_amdgcn_exp2f)
    return __builtin_amdgcn_exp2f(x);
#else
    return exp2f(x);
#endif
}

// DPP helpers (VALU pipe, no DS).  ctrl: 0xB1 quad_perm xor1, 0x4E xor2,
// 0x124 row_ror:4, 0x128 row_ror:8, j*0x55 quad_perm broadcast-lane-j.
template<int CTRL>
__device__ __forceinline__ float dpp_add(float x) {
    const int xi = __float_as_int(x);
    const int yi = __builtin_amdgcn_update_dpp(0, xi, CTRL, 0xF, 0xF, true);
    return x + __int_as_float(yi);
}
template<int CTRL>
__device__ __forceinline__ float dpp_mov(float x) {
    const int xi = __float_as_int(x);
    const int yi = __builtin_amdgcn_update_dpp(0, xi, CTRL, 0xF, 0xF, true);
    return __int_as_float(yi);
}

// ---------------- K0: qh = Wc @ query + bc  (256 outputs, once) -------------
__global__ void qh_kernel(const float* __restrict__ Wc,
                          const float* __restrict__ query,
                          const float* __restrict__ bc,
                          float* __restrict__ qh) {
    const int i = threadIdx.x;  // 0..255
    float acc = bc[i];
    #pragma unroll
    for (int k = 0; k < NE; k += 4) {
        const float4 w = *reinterpret_cast<const float4*>(Wc + i * NE + k);
        const float4 q = *reinterpret_cast<const float4*>(query + k);
        acc += w.x * q.x + w.y * q.y + w.z * q.z + w.w * q.w;
    }
    qh[i] = acc;
}

// ---------------- K1: single-pass logits + weighted partials ----------------
// R18 = R16 (best, 39.57us) + ONLY trim (a) from R17 (the R17 bundle with
// unroll 8 regressed; unroll stays 4): rtL := rtemp*log2e pre-folded into
// wl/A at setup (they feed ONLY the logit path) -> per-row weight becomes
// w = m * 2^(ssel + C2L): -2 VALU/iter, and the mask load leaves the exp
// dependency chain.
// 16-lane group owns one row: lane quad e = 4*(lane&15)+j, row group=lane>>4.
// tanh(x+qh) Taylor-expanded in qh (|qh|<=~0.006).  Z-counting: each lane's
// scalar zacc covers class lane&3; quads within a row are redundant copies,
// deduplicated in the epilogue by taking quad-0 lanes after xor16/32.
template<int CHUNKS>
__global__ __launch_bounds__(256, 4) void pool1_kernel(
    const float* __restrict__ vertices,
    const float* __restrict__ mask,
    const float* __restrict__ qh,
    const float* __restrict__ wl,
    const float* __restrict__ blp,
    const float* __restrict__ tempp,
    float* __restrict__ partN,    // [NN][CHUNKS][NH][NE]
    float* __restrict__ partZ)    // [NN][CHUNKS][NH]
{
    constexpr int ROWS_B = NV / CHUNKS;   // rows per block   (256 @ CHUNKS=8)
    constexpr int ROWS_W = ROWS_B / 4;    // rows per wave    (64)
    constexpr int ITERS  = ROWS_W / 4;    // 4 rows per iter  (16)
    constexpr float L2E  = 1.4426950408889634f;   // log2(e)

    __shared__ float sp[4][NH][NE];   // 4 KB
    __shared__ float sz[4][NH];

    const int tid   = threadIdx.x;
    const int lane  = tid & 63;
    const int wid   = tid >> 6;
    const int n     = blockIdx.x / CHUNKS;
    const int chunk = blockIdx.x % CHUNKS;
    const int eq    = (lane & 15) * 4;    // e-quad base for this lane
    const int rg    = lane >> 4;          // row group 0..3 (16-lane DPP rows)
    const bool c0   = (lane & 1) != 0;    // head-class select bits (hoisted)
    const bool c1   = (lane & 2) != 0;

    const float bl    = blp[0];
    const float rtemp = 1.0f / tempp[0];
    const float rtL   = rtemp * L2E;      // logit scale in log2 domain
    const float C2L   = bl * rtL;         // additive const in log2 domain

    // Per-lane constants straight from global (qh is 1 KB, L2-hot).
    // wl/A feed ONLY the logit path -> pre-scale by rtL here (trim a).
    const vf4 wlf = *reinterpret_cast<const vf4*>(wl + eq);
    f2 wl01 = __builtin_shufflevector(wlf, wlf, 0, 1);
    f2 wl23 = __builtin_shufflevector(wlf, wlf, 2, 3);
    f2 A01[NH], A23[NH];   // rtL * wl_j * qh[h][eq+j]
    #pragma unroll
    for (int h = 0; h < NH; ++h) {
        const vf4 q = *reinterpret_cast<const vf4*>(qh + h * NE + eq);
        A01[h] = (wl01 * rtL) * __builtin_shufflevector(q, q, 0, 1);
        A23[h] = (wl23 * rtL) * __builtin_shufflevector(q, q, 2, 3);
    }
    wl01 = wl01 * rtL;
    wl23 = wl23 * rtL;

    f2 nacc01[NH] = {}, nacc23[NH] = {};
    float zacc = 0.f;                          // class h = lane&3

    const float* vb = vertices + (size_t)n * NV * NE;
    const float* mb = mask + (size_t)n * NV;
    const int rbase = chunk * ROWS_B + wid * ROWS_W;

    #pragma unroll 4
    for (int it = 0; it < ITERS; ++it) {
        const int row = rbase + it * 4 + rg;
        const vf4   x = *reinterpret_cast<const vf4*>(vb + (size_t)row * NE + eq);
        const float m = mb[row];
        const f2 x01 = __builtin_shufflevector(x, x, 0, 1);
        const f2 x23 = __builtin_shufflevector(x, x, 2, 3);

        // t = tanh(x) = 1 - 2/(2^{2L2E*x}+1); u = 1 - t^2; s0 = sum wl*t
        const f2 z01 = x01 * (2.0f * L2E);           // pk_mul (folds exp's mul)
        const f2 z23 = x23 * (2.0f * L2E);
        f2 e01, e23;
        e01.x = exp2r(z01.x); e01.y = exp2r(z01.y);  // raw v_exp_f32
        e23.x = exp2r(z23.x); e23.y = exp2r(z23.y);
        const f2 d01 = e01 + 1.0f;
        const f2 d23 = e23 + 1.0f;
        f2 r01, r23;
        r01.x = __builtin_amdgcn_rcpf(d01.x); r01.y = __builtin_amdgcn_rcpf(d01.y);
        r23.x = __builtin_amdgcn_rcpf(d23.x); r23.y = __builtin_amdgcn_rcpf(d23.y);
        f2 m2; m2.x = -2.0f; m2.y = -2.0f;
        f2 one; one.x = 1.0f; one.y = 1.0f;
        const f2 t01 = fma2(m2, r01, one);
        const f2 t23 = fma2(m2, r23, one);
        const f2 u01 = fma2(-t01, t01, one);
        const f2 u23 = fma2(-t23, t23, one);
        f2 s0v = fma2(wl23, t23, wl01 * t01);        // already rtL-scaled

        // per-head partial -> 2-step quad sums (all 4 lanes of quad hold it)
        float q4[NH];
        #pragma unroll
        for (int h = 0; h < NH; ++h) {
            const f2 shv = fma2(A01[h], u01, fma2(A23[h], u23, s0v));
            float v = shv.x + shv.y;
            v = dpp_add<0xB1>(v);    // + lane^1
            v = dpp_add<0x4E>(v);    // + lane^2  -> quad sum
            q4[h] = v;
        }
        // lane class j = lane&3 picks head j; ror4+ror8 completes the row sum
        float ssel = c1 ? (c0 ? q4[3] : q4[2]) : (c0 ? q4[1] : q4[0]);
        ssel = dpp_add<0x124>(ssel);   // + row_ror:4
        ssel = dpp_add<0x128>(ssel);   // + row_ror:8 -> s[class] for this row
        // w for this lane's class: m * 2^(ssel + C2L); masked rows -> 0 exactly
        const float wsel = m * exp2r(ssel + C2L);
        zacc += wsel;
        // regather all 4 heads' w from within the quad
        const float w0 = dpp_mov<0x00>(wsel);
        const float w1 = dpp_mov<0x55>(wsel);
        const float w2 = dpp_mov<0xAA>(wsel);
        const float w3 = dpp_mov<0xFF>(wsel);
        f2 wv;
        wv.x = w0; wv.y = w0; nacc01[0] = fma2(wv, x01, nacc01[0]); nacc23[0] = fma2(wv, x23, nacc23[0]);
        wv.x = w1; wv.y = w1; nacc01[1] = fma2(wv, x01, nacc01[1]); nacc23[1] = fma2(wv, x23, nacc23[1]);
        wv.x = w2; wv.y = w2; nacc01[2] = fma2(wv, x01, nacc01[2]); nacc23[2] = fma2(wv, x23, nacc23[2]);
        wv.x = w3; wv.y = w3; nacc01[3] = fma2(wv, x01, nacc01[3]); nacc23[3] = fma2(wv, x23, nacc23[3]);
    }

    // unpack accumulators, reduce across the 4 row-groups
    float nacc[NH][4];
    #pragma unroll
    for (int h = 0; h < NH; ++h) {
        nacc[h][0] = nacc01[h].x; nacc[h][1] = nacc01[h].y;
        nacc[h][2] = nacc23[h].x; nacc[h][3] = nacc23[h].y;
    }
    #pragma unroll
    for (int off = 16; off <= 32; off <<= 1) {
        #pragma unroll
        for (int h = 0; h < NH; ++h) {
            #pragma unroll
            for (int j = 0; j < 4; ++j)
                nacc[h][j] += __shfl_xor(nacc[h][j], off, 64);
        }
        zacc += __shfl_xor(zacc, off, 64);
    }
    // zacc now: lane L holds sum over row-groups for class L&3, quad (L>>2)&3.
    // Quads are redundant copies of the same rows -> take quad 0 only.

    // cross-wave combine in LDS, then one partial per block to ws
    if (rg == 0) {  // lanes 0..15 hold the reduced values; eq = lane*4
        #pragma unroll
        for (int h = 0; h < NH; ++h) {
            sp[wid][h][eq + 0] = nacc[h][0];
            sp[wid][h][eq + 1] = nacc[h][1];
            sp[wid][h][eq + 2] = nacc[h][2];
            sp[wid][h][eq + 3] = nacc[h][3];
        }
        if (lane < NH) sz[wid][lane] = zacc;   // lane h = class h, quad 0
    }
    __syncthreads();
    {
        const int h = tid >> 6, e = tid & 63;
        const float v = sp[0][h][e] + sp[1][h][e] + sp[2][h][e] + sp[3][h][e];
        partN[(((size_t)n * CHUNKS + chunk) * NH + h) * NE + e] = v;
    }
    if (tid < NH) {
        const float z = sz[0][tid] + sz[1][tid] + sz[2][tid] + sz[3][tid];
        partZ[((size_t)n * CHUNKS + chunk) * NH + tid] = z;
    }
}

// ---------------- K2: reduce chunks, normalize, leaky, Wr matvec ------------
__global__ __launch_bounds__(256) void pool2_kernel(
    int chunks,
    const float* __restrict__ partN,
    const float* __restrict__ partZ,
    const float* __restrict__ Wr,
    const float* __restrict__ br,
    float* __restrict__ out)
{
    __shared__ float heads[NH * NE];
    const int n = blockIdx.x, tid = threadIdx.x;
    const int h = tid >> 6, e = tid & 63;

    float num = 0.f, Z = 0.f;
    for (int c = 0; c < chunks; ++c) {
        num += partN[(((size_t)n * chunks + c) * NH + h) * NE + e];
        Z   += partZ[((size_t)n * chunks + c) * NH + h];
    }
    const float val = num / Z;
    heads[tid] = (val > 0.f) ? val : 0.01f * val;
    __syncthreads();

    // out[n,e] = br[e] + sum_k heads[k] * Wr[e*256+k]; quad-split over k
    {
        const int eo = tid >> 2;          // 0..63 output element
        const int ko = (tid & 3) * 64;    // k sub-range
        float acc = 0.f;
        #pragma unroll
        for (int k = 0; k < 64; k += 4) {
            const float4 w = *reinterpret_cast<const float4*>(Wr + eo * (NH * NE) + ko + k);
            acc += heads[ko + k + 0] * w.x + heads[ko + k + 1] * w.y +
                   heads[ko + k + 2] * w.z + heads[ko + k + 3] * w.w;
        }
        acc += __shfl_xor(acc, 1, 64);
        acc += __shfl_xor(acc, 2, 64);
        if ((tid & 3) == 0) out[(size_t)n * NE + eo] = acc + br[eo];
    }
}

extern "C" void kernel_launch(void* const* d_in, const int* in_sizes, int n_in,
                              void* d_out, int out_size, void* d_ws, size_t ws_size,
                              hipStream_t stream) {
    const float* vertices = (const float*)d_in[0];
    const float* mask     = (const float*)d_in[1];
    const float* query    = (const float*)d_in[2];
    const float* Wc       = (const float*)d_in[3];
    const float* bc       = (const float*)d_in[4];
    const float* wl       = (const float*)d_in[5];
    const float* bl       = (const float*)d_in[6];
    const float* Wr       = (const float*)d_in[7];
    const float* br       = (const float*)d_in[8];
    const float* temp     = (const float*)d_in[9];
    float* out = (float*)d_out;

    // ws layout (floats): qh[256] | partZ[NN*chunks*NH] | partN[NN*chunks*NH*NE]
    auto need = [](int chunks) -> size_t {
        return (size_t)(256 + NN * chunks * NH + (size_t)NN * chunks * NH * NE) * 4;
    };
    int chunks = 8;
    while (chunks > 1 && need(chunks) > ws_size) chunks >>= 1;

    float* qh    = (float*)d_ws;
    float* partZ = qh + 256;
    float* partN = partZ + (size_t)NN * chunks * NH;

    qh_kernel<<<1, 256, 0, stream>>>(Wc, query, bc, qh);
    switch (chunks) {
        case 8:  pool1_kernel<8><<<NN * 8, 256, 0, stream>>>(vertices, mask, qh, wl, bl, temp, partN, partZ); break;
        case 4:  pool1_kernel<4><<<NN * 4, 256, 0, stream>>>(vertices, mask, qh, wl, bl, temp, partN, partZ); break;
        case 2:  pool1_kernel<2><<<NN * 2, 256, 0, stream>>>(vertices, mask, qh, wl, bl, temp, partN, partZ); break;
        default: pool1_kernel<1><<<NN * 1, 256, 0, stream>>>(vertices, mask, qh, wl, bl, temp, partN, partZ); break;
    }
    pool2_kernel<<<NN, 256, 0, stream>>>(chunks, partN, partZ, Wr, br, out);
}